// Round 8
// baseline (14151.654 us; speedup 1.0000x reference)
//
#include <hip/hip_runtime.h>
#include <hip/hip_bf16.h>

// LSNN adaptive-LIF scan, T=1000, B=64, N_in=256, N_h=512, fp32.
//
// BITWISE CONSTRAINT (rounds 2-7): harness compares binary spikes exactly;
// flips cascade. The recurrent term for column n MUST be one serial
// ascending-index __fadd_rn chain over active neurons (== numpy/OpenBLAS
// sequential-k order; fma(0,w,c)=c). Pad rows are +0.0 (bitwise no-op).
//
// Round 8: r7 hit the per-CU L2 read roofline (~69 B/cy) with only 64 CUs
// active (cnt~200 spikes -> 400 KB/step/WG). Split each batch across 4 WGs
// (256 WGs x 128 thr, 128 cols each) -> 4x less traffic per CU. Cross-WG
// spike exchange via agent-scope atomics in ws: publish ballot words +
// per-batch counter at step top (release, fire-and-forget), gather overlaps
// the latency, poll counter >= 8*(t+1) (acquire) after gather, read 8 mask
// words, rebuild list locally (identical ascending order -> bit-identical).

#define TT   1000
#define BB   64
#define NIN  256
#define NH   512
#define TS   16                          // gather tile size
#define PADOFF (NH * 2048)               // byte offset of zeroed row 512 of wT

__device__ constexpr float KV = (float)(0.001 * 100.0);            // DT*TAU_MEM_INV
__device__ constexpr float KI = (float)(0.001 * 200.0);            // DT*TAU_SYN_INV
__device__ constexpr float KB = (float)(0.001 * (1.0 / 800.0));    // DT*TAU_ADAPT_INV
__device__ constexpr float KJ = (float)((1.0 / 800.0) * 1.8);      // TAU_ADAPT_INV*BETA

// ---------------- transpose w_rec (512x512): wT[j][n] = w_rec[n][j] ----------
__global__ void transp512(const float* __restrict__ in, float* __restrict__ ot) {
    __shared__ float tile[32][33];
    const int tx = threadIdx.x;            // 0..31
    const int ty = threadIdx.y;            // 0..7
    const int jcol = blockIdx.x * 32 + tx;
    const int row0 = blockIdx.y * 32;
    for (int r = ty; r < 32; r += 8)
        tile[r][tx] = in[(size_t)(row0 + r) * NH + jcol];
    __syncthreads();
    const int ncol = blockIdx.y * 32 + tx;
    const int jrow0 = blockIdx.x * 32;
    for (int r = ty; r < 32; r += 8)
        ot[(size_t)(jrow0 + r) * NH + ncol] = tile[tx][r];
}

// zero row 512 of wT (padding target) + zero the flag region
__global__ void zrow(float* __restrict__ wT, unsigned long long* __restrict__ flags) {
    wT[(size_t)NH * NH + threadIdx.x] = 0.0f;
    // flags region: 64 counters (128B stride = 1024 u64) + 64*2*8 mask words
    for (int i = threadIdx.x; i < 1024 + 1024; i += NH)
        flags[i] = 0ull;
}

// ---------------- fp32 GEMM: F[m][n] = sum_k X[m][k] * W[n][k] ---------------
// UNCHANGED from round 2 (bitwise-verified against the np reference).
__global__ __launch_bounds__(256)
void gemm_ff(const float* __restrict__ X, const float* __restrict__ W,
             float* __restrict__ F, int M) {
    const int bx = blockIdx.x;   // n-tile: 0..3
    const int by = blockIdx.y;   // m-tile
    const int tid = threadIdx.x;

    __shared__ float As[32][128];
    __shared__ float Bs[32][128];

    const int tn0 = (tid & 15) * 8;
    const int tm0 = (tid >> 4) * 8;
    float acc[8][8] = {};

    const int am = tid >> 1;
    const int aq = (tid & 1) * 4;

    const float* Xb = X + (size_t)(by * 128 + am) * NIN;
    const float* Wb = W + (size_t)(bx * 128 + am) * NIN;

    for (int k0 = 0; k0 < NIN; k0 += 32) {
        __syncthreads();
#pragma unroll
        for (int i2 = 0; i2 < 4; ++i2) {
            const int q = aq + i2;
            float4 xa = *reinterpret_cast<const float4*>(Xb + k0 + q * 4);
            As[q * 4 + 0][am] = xa.x; As[q * 4 + 1][am] = xa.y;
            As[q * 4 + 2][am] = xa.z; As[q * 4 + 3][am] = xa.w;
            float4 wa = *reinterpret_cast<const float4*>(Wb + k0 + q * 4);
            Bs[q * 4 + 0][am] = wa.x; Bs[q * 4 + 1][am] = wa.y;
            Bs[q * 4 + 2][am] = wa.z; Bs[q * 4 + 3][am] = wa.w;
        }
        __syncthreads();
#pragma unroll 8
        for (int kk = 0; kk < 32; ++kk) {
            float4 a0 = *reinterpret_cast<const float4*>(&As[kk][tm0]);
            float4 a1 = *reinterpret_cast<const float4*>(&As[kk][tm0 + 4]);
            float4 b0 = *reinterpret_cast<const float4*>(&Bs[kk][tn0]);
            float4 b1 = *reinterpret_cast<const float4*>(&Bs[kk][tn0 + 4]);
            const float av[8] = {a0.x, a0.y, a0.z, a0.w, a1.x, a1.y, a1.z, a1.w};
            const float bv[8] = {b0.x, b0.y, b0.z, b0.w, b1.x, b1.y, b1.z, b1.w};
#pragma unroll
            for (int i = 0; i < 8; ++i)
#pragma unroll
                for (int j = 0; j < 8; ++j)
                    acc[i][j] += av[i] * bv[j];
        }
    }

    float* Fo = F + (size_t)(by * 128 + tm0) * NH + bx * 128 + tn0;
#pragma unroll
    for (int i = 0; i < 8; ++i) {
        *reinterpret_cast<float4*>(Fo + (size_t)i * NH) =
            make_float4(acc[i][0], acc[i][1], acc[i][2], acc[i][3]);
        *reinterpret_cast<float4*>(Fo + (size_t)i * NH + 4) =
            make_float4(acc[i][4], acc[i][5], acc[i][6], acc[i][7]);
    }
}

// ---------------- gather tile helpers (r7-proven) ----------------------------
__device__ __forceinline__ void fill_tile(float (&buf)[TS], const int* lp,
                                          int base, const char* wb,
                                          unsigned n4) {
#pragma unroll
    for (int i = 0; i < TS; i += 4) {
        const int4 o = *reinterpret_cast<const int4*>(lp + base + i);
        buf[i + 0] = *reinterpret_cast<const float*>(wb + (unsigned)(o.x + (int)n4));
        buf[i + 1] = *reinterpret_cast<const float*>(wb + (unsigned)(o.y + (int)n4));
        buf[i + 2] = *reinterpret_cast<const float*>(wb + (unsigned)(o.z + (int)n4));
        buf[i + 3] = *reinterpret_cast<const float*>(wb + (unsigned)(o.w + (int)n4));
    }
}
__device__ __forceinline__ void add_tile(const float (&buf)[TS], float& rec) {
#pragma unroll
    for (int i = 0; i < TS; ++i) rec = __fadd_rn(rec, buf[i]);
}

// build ascending list from 8 x 64-bit words in LDS; returns total count.
// thread tid handles bits 4*tid .. 4*tid+3 (128 threads x 4 = 512 bits).
__device__ __forceinline__ int build_list(const unsigned long long* words,
                                          int* list, int tid) {
    unsigned long long w[8];
    int pc[8];
#pragma unroll
    for (int k = 0; k < 8; ++k) { w[k] = words[k]; pc[k] = __popcll(w[k]); }
    const int p  = tid << 2;
    const int wi = p >> 6;
    const int bi = p & 63;
    int base = 0;
#pragma unroll
    for (int k = 0; k < 8; ++k) if (k < wi) base += pc[k];
    base += __popcll(w[wi] & ((1ull << bi) - 1ull));   // bi in [0,60], no UB
#pragma unroll
    for (int i = 0; i < 4; ++i) {
        if ((w[wi] >> (bi + i)) & 1ull) { list[base] = (p + i) << 11; ++base; }
    }
    int tot = 0;
#pragma unroll
    for (int k = 0; k < 8; ++k) tot += pc[k];
    return tot;
}

// ---------------- scan kernel: 4 WGs (128 thr) per batch element -------------
// st layout: [z | v | i | b], each BB*NH floats.
// flags: gcnt[b] at flags + b*16 (128B stride); masks at flags + 1024,
//        word index ((b*2+par)*8 + w).
__global__ __launch_bounds__(128)
void lsnn_scan(const float* __restrict__ F, const float* __restrict__ wT,
               const float* __restrict__ z0, const float* __restrict__ v0,
               const float* __restrict__ i0, const float* __restrict__ b0,
               float* __restrict__ out, float* __restrict__ st,
               unsigned long long* __restrict__ flags,
               int t0, int Tc, int first, int last) {
    const int tid  = threadIdx.x;        // 0..127
    const int b    = blockIdx.x & 63;    // batch (same-XCD quarters: blk%8==b%8)
    const int q    = blockIdx.x >> 6;    // quarter 0..3
    const int col  = (q << 7) + tid;     // owned column
    const int lane = tid & 63;
    const int wv   = tid >> 6;           // wave 0..1
    const size_t bn = (size_t)b * NH + col;

    __shared__ __align__(16) int list[NH + 2 * TS];
    __shared__ unsigned long long words[8];

    unsigned long long* gcnt  = flags + (size_t)b * 16;
    unsigned long long* gmask = flags + 1024;

    float v, cur, bb, zprev;
    if (first) {
        zprev = z0[bn]; v = v0[bn]; cur = i0[bn]; bb = b0[bn];
    } else {
        zprev = st[0 * BB * NH + bn];
        v     = st[1 * BB * NH + bn];
        cur   = st[2 * BB * NH + bn];
        bb    = st[3 * BB * NH + bn];
    }

    // ---- initial list: read the full z-plane of batch b directly -----------
    {
        const float* zsrc = first ? z0 : (st + 0 * BB * NH);
#pragma unroll
        for (int r = 0; r < 4; ++r) {
            const float zv = zsrc[(size_t)b * NH + (r << 7) + tid];
            const unsigned long long m = __ballot(zv > 0.0f);
            if (lane == 0) words[(r << 1) + wv] = m;
        }
        __syncthreads();
    }
    int cnt = build_list(words, list, tid);
    if (tid < 2 * TS) list[cnt + tid] = PADOFF;
    __syncthreads();

    const char*  wb = reinterpret_cast<const char*>(wT);   // uniform base (SGPR)
    const unsigned n4 = (unsigned)col * 4u;                // column byte offset
    const float* Fp = F + (size_t)b * NH + col;
    float* op = out + ((size_t)t0 * BB + b) * NH + col;

    for (int t = 0; t < Tc; ++t) {
        const int tglob = t0 + t;
        const int par   = tglob & 1;

        // ---- t.1: prefetch F, elementwise update, publish spikes ------------
        const float fval = Fp[(size_t)t * BB * NH];   // consumed after gather
        const float v_dec = __fadd_rn(v, __fmul_rn(KV, __fadd_rn(__fsub_rn(0.0f, v), cur)));
        const float i_dec = __fsub_rn(cur, __fmul_rn(KI, cur));
        const float b_dec = __fadd_rn(bb, __fmul_rn(KB, __fsub_rn(1.0f, bb)));
        const float zn = (__fsub_rn(v_dec, b_dec) > 0.0f) ? 1.0f : 0.0f;
        v  = (zn > 0.0f) ? 0.0f : v_dec;
        bb = __fadd_rn(b_dec, __fmul_rn(zn, KJ));
        op[0] = zn;
        op += (size_t)BB * NH;
        const unsigned long long mm = __ballot(zn > 0.0f);
        if (lane == 0) {
            __hip_atomic_store(&gmask[((size_t)(b * 2 + par)) * 8 + (q * 2 + wv)],
                               mm, __ATOMIC_RELEASE, __HIP_MEMORY_SCOPE_AGENT);
            __hip_atomic_fetch_add(gcnt, 1ull, __ATOMIC_RELEASE,
                                   __HIP_MEMORY_SCOPE_AGENT);
        }

        // ---- t.2: pipelined serial gather over list (prev spikes) -----------
        float rec = 0.0f;
        if (cnt > 0) {
            const int* lp = list;
            float bufA[TS], bufB[TS];
            fill_tile(bufA, lp, 0, wb, n4);
            __builtin_amdgcn_sched_barrier(0);
            int kt = 0;
            for (;;) {
                fill_tile(bufB, lp, kt + TS, wb, n4);
                __builtin_amdgcn_sched_barrier(0);
                add_tile(bufA, rec);
                kt += TS;
                if (kt >= cnt) break;
                fill_tile(bufA, lp, kt + TS, wb, n4);
                __builtin_amdgcn_sched_barrier(0);
                add_tile(bufB, rec);
                kt += TS;
                if (kt >= cnt) break;
            }
        }
        cur = __fadd_rn(__fadd_rn(i_dec, fval), rec);
        zprev = zn;

        // ---- t.3: poll exchange, rebuild list for next step -----------------
        if (t < Tc - 1) {
            if (tid == 0) {
                const unsigned long long target = 8ull * (unsigned long long)(tglob + 1);
                int guard = 0;
                while (__hip_atomic_load(gcnt, __ATOMIC_ACQUIRE,
                                         __HIP_MEMORY_SCOPE_AGENT) < target) {
                    __builtin_amdgcn_s_sleep(2);
                    if (++guard > (1 << 26)) break;   // wrong-answer > hang
                }
            }
            __syncthreads();   // poll done; gather's list reads complete
            if (tid < 8)
                words[tid] = __hip_atomic_load(&gmask[((size_t)(b * 2 + par)) * 8 + tid],
                                               __ATOMIC_ACQUIRE, __HIP_MEMORY_SCOPE_AGENT);
            __syncthreads();   // words published
            cnt = build_list(words, list, tid);
            if (tid < 2 * TS) list[cnt + tid] = PADOFF;
            __syncthreads();   // list ready for next gather
        }
    }

    st[0 * BB * NH + bn] = zprev;
    st[1 * BB * NH + bn] = v;
    st[2 * BB * NH + bn] = cur;
    st[3 * BB * NH + bn] = bb;
    if (last) {
        float* tail = out + (size_t)TT * BB * NH;
        tail[0 * BB * NH + bn] = zprev;  // zT
        tail[1 * BB * NH + bn] = v;      // vT
        tail[2 * BB * NH + bn] = cur;    // iT
        tail[3 * BB * NH + bn] = bb;     // bT
    }
}

// ---------------------------------------------------------------------------
extern "C" void kernel_launch(void* const* d_in, const int* in_sizes, int n_in,
                              void* d_out, int out_size, void* d_ws, size_t ws_size,
                              hipStream_t stream) {
    const float* X     = (const float*)d_in[0];
    const float* z0    = (const float*)d_in[1];
    const float* v0    = (const float*)d_in[2];
    const float* i0    = (const float*)d_in[3];
    const float* b0    = (const float*)d_in[4];
    const float* w_in  = (const float*)d_in[5];
    const float* w_rec = (const float*)d_in[6];
    float* out = (float*)d_out;

    char* ws = (char*)d_ws;
    float* wT = (float*)ws;                                    // 1 MB + zero row
    const size_t wT_bytes = ((size_t)NH * NH + NH) * 4 + 2048;
    float* st = (float*)(ws + wT_bytes);                       // 512 KB
    unsigned long long* flags =
        (unsigned long long*)(ws + wT_bytes + (512u << 10));   // 16 KB
    char*  fbase = ws + wT_bytes + (512u << 10) + (16u << 10);

    const long long per = (long long)BB * NH * 4;              // bytes/step of F
    long long avail = (long long)ws_size -
                      (long long)(wT_bytes + (512u << 10) + (16u << 10));
    int Tc;
    if (avail >= 2 * per * TT) {
        Tc = TT;
    } else {
        Tc = (int)(avail / (2 * per));
        if (Tc > TT) Tc = TT;
        Tc &= ~1;
        if (Tc < 2) Tc = 2;
    }
    const size_t fbytes = (size_t)Tc * per;
    float* Fb[2] = { (float*)fbase, (float*)(fbase + fbytes) };

    transp512<<<dim3(16, 16), dim3(32, 8), 0, stream>>>(w_rec, wT);
    zrow<<<1, NH, 0, stream>>>(wT, flags);

    int t0 = 0, buf = 0;
    bool firstc = true;
    while (t0 < TT) {
        const int Tcur = (Tc < TT - t0) ? Tc : (TT - t0);
        const int Mc = Tcur * BB;
        gemm_ff<<<dim3(4, Mc / 128), 256, 0, stream>>>(
            X + (size_t)t0 * BB * NIN, w_in, Fb[buf], Mc);
        lsnn_scan<<<dim3(256), dim3(128), 0, stream>>>(
            Fb[buf], wT, z0, v0, i0, b0, out, st, flags,
            t0, Tcur, firstc ? 1 : 0, (t0 + Tcur >= TT) ? 1 : 0);
        firstc = false;
        buf ^= 1;
        t0 += Tcur;
    }
}

// Round 9
// 10469.917 us; speedup vs baseline: 1.3516x; 1.3516x over previous
//
#include <hip/hip_runtime.h>
#include <hip/hip_bf16.h>

// LSNN adaptive-LIF scan, T=1000, B=64, N_in=256, N_h=512, fp32.
//
// BITWISE CONSTRAINT (rounds 2-7): harness compares binary spikes exactly;
// flips cascade. The recurrent term for column n MUST be one serial
// ascending-index __fadd_rn chain over active neurons (== numpy/OpenBLAS
// sequential-k order; fma(0,w,c)=c). Pad rows are +0.0 (bitwise no-op).
//
// Round 9: r8 proved the 4-WG-per-batch split correct but its shared-counter
// atomics serialized (~33k cy/step, VALUBusy 2%). Replace with contention-
// free exchange: per-writer 128B-cacheline slots, mask store (relaxed) +
// tag store (release), parity double-buffered; readers poll 8 distinct tags
// (acquire) then load masks. No RMW, no shared-line ping-pong. Overwrite
// safety: writer reaches t+2 publish only after seeing reader's t+1 publish,
// which is after reader's t mask read (vmcnt drained at barrier).

#define TT   1000
#define BB   64
#define NIN  256
#define NH   512
#define TS   16                          // gather tile size
#define PADOFF (NH * 2048)               // byte offset of zeroed row 512 of wT

__device__ constexpr float KV = (float)(0.001 * 100.0);            // DT*TAU_MEM_INV
__device__ constexpr float KI = (float)(0.001 * 200.0);            // DT*TAU_SYN_INV
__device__ constexpr float KB = (float)(0.001 * (1.0 / 800.0));    // DT*TAU_ADAPT_INV
__device__ constexpr float KJ = (float)((1.0 / 800.0) * 1.8);      // TAU_ADAPT_INV*BETA

// ---------------- transpose w_rec (512x512): wT[j][n] = w_rec[n][j] ----------
__global__ void transp512(const float* __restrict__ in, float* __restrict__ ot) {
    __shared__ float tile[32][33];
    const int tx = threadIdx.x;            // 0..31
    const int ty = threadIdx.y;            // 0..7
    const int jcol = blockIdx.x * 32 + tx;
    const int row0 = blockIdx.y * 32;
    for (int r = ty; r < 32; r += 8)
        tile[r][tx] = in[(size_t)(row0 + r) * NH + jcol];
    __syncthreads();
    const int ncol = blockIdx.y * 32 + tx;
    const int jrow0 = blockIdx.x * 32;
    for (int r = ty; r < 32; r += 8)
        ot[(size_t)(jrow0 + r) * NH + ncol] = tile[tx][r];
}

// zero row 512 of wT (padding target) + zero the exchange slots (128 KB)
__global__ void zrow(float* __restrict__ wT, unsigned long long* __restrict__ flags) {
    wT[(size_t)NH * NH + threadIdx.x] = 0.0f;
    // slots: 64 batches x 2 parities x 8 writers x 16 u64 (128 B) = 16384 u64
    for (int i = threadIdx.x; i < 16384; i += NH)
        flags[i] = 0ull;
}

// ---------------- fp32 GEMM: F[m][n] = sum_k X[m][k] * W[n][k] ---------------
// UNCHANGED from round 2 (bitwise-verified against the np reference).
__global__ __launch_bounds__(256)
void gemm_ff(const float* __restrict__ X, const float* __restrict__ W,
             float* __restrict__ F, int M) {
    const int bx = blockIdx.x;   // n-tile: 0..3
    const int by = blockIdx.y;   // m-tile
    const int tid = threadIdx.x;

    __shared__ float As[32][128];
    __shared__ float Bs[32][128];

    const int tn0 = (tid & 15) * 8;
    const int tm0 = (tid >> 4) * 8;
    float acc[8][8] = {};

    const int am = tid >> 1;
    const int aq = (tid & 1) * 4;

    const float* Xb = X + (size_t)(by * 128 + am) * NIN;
    const float* Wb = W + (size_t)(bx * 128 + am) * NIN;

    for (int k0 = 0; k0 < NIN; k0 += 32) {
        __syncthreads();
#pragma unroll
        for (int i2 = 0; i2 < 4; ++i2) {
            const int q = aq + i2;
            float4 xa = *reinterpret_cast<const float4*>(Xb + k0 + q * 4);
            As[q * 4 + 0][am] = xa.x; As[q * 4 + 1][am] = xa.y;
            As[q * 4 + 2][am] = xa.z; As[q * 4 + 3][am] = xa.w;
            float4 wa = *reinterpret_cast<const float4*>(Wb + k0 + q * 4);
            Bs[q * 4 + 0][am] = wa.x; Bs[q * 4 + 1][am] = wa.y;
            Bs[q * 4 + 2][am] = wa.z; Bs[q * 4 + 3][am] = wa.w;
        }
        __syncthreads();
#pragma unroll 8
        for (int kk = 0; kk < 32; ++kk) {
            float4 a0 = *reinterpret_cast<const float4*>(&As[kk][tm0]);
            float4 a1 = *reinterpret_cast<const float4*>(&As[kk][tm0 + 4]);
            float4 b0 = *reinterpret_cast<const float4*>(&Bs[kk][tn0]);
            float4 b1 = *reinterpret_cast<const float4*>(&Bs[kk][tn0 + 4]);
            const float av[8] = {a0.x, a0.y, a0.z, a0.w, a1.x, a1.y, a1.z, a1.w};
            const float bv[8] = {b0.x, b0.y, b0.z, b0.w, b1.x, b1.y, b1.z, b1.w};
#pragma unroll
            for (int i = 0; i < 8; ++i)
#pragma unroll
                for (int j = 0; j < 8; ++j)
                    acc[i][j] += av[i] * bv[j];
        }
    }

    float* Fo = F + (size_t)(by * 128 + tm0) * NH + bx * 128 + tn0;
#pragma unroll
    for (int i = 0; i < 8; ++i) {
        *reinterpret_cast<float4*>(Fo + (size_t)i * NH) =
            make_float4(acc[i][0], acc[i][1], acc[i][2], acc[i][3]);
        *reinterpret_cast<float4*>(Fo + (size_t)i * NH + 4) =
            make_float4(acc[i][4], acc[i][5], acc[i][6], acc[i][7]);
    }
}

// ---------------- gather tile helpers (r7-proven) ----------------------------
__device__ __forceinline__ void fill_tile(float (&buf)[TS], const int* lp,
                                          int base, const char* wb,
                                          unsigned n4) {
#pragma unroll
    for (int i = 0; i < TS; i += 4) {
        const int4 o = *reinterpret_cast<const int4*>(lp + base + i);
        buf[i + 0] = *reinterpret_cast<const float*>(wb + (unsigned)(o.x + (int)n4));
        buf[i + 1] = *reinterpret_cast<const float*>(wb + (unsigned)(o.y + (int)n4));
        buf[i + 2] = *reinterpret_cast<const float*>(wb + (unsigned)(o.z + (int)n4));
        buf[i + 3] = *reinterpret_cast<const float*>(wb + (unsigned)(o.w + (int)n4));
    }
}
__device__ __forceinline__ void add_tile(const float (&buf)[TS], float& rec) {
#pragma unroll
    for (int i = 0; i < TS; ++i) rec = __fadd_rn(rec, buf[i]);
}

// build ascending list from 8 x 64-bit words in LDS; returns total count.
// thread tid handles bits 4*tid .. 4*tid+3 (128 threads x 4 = 512 bits).
__device__ __forceinline__ int build_list(const unsigned long long* words,
                                          int* list, int tid) {
    unsigned long long w[8];
    int pc[8];
#pragma unroll
    for (int k = 0; k < 8; ++k) { w[k] = words[k]; pc[k] = __popcll(w[k]); }
    const int p  = tid << 2;
    const int wi = p >> 6;
    const int bi = p & 63;
    int base = 0;
#pragma unroll
    for (int k = 0; k < 8; ++k) if (k < wi) base += pc[k];
    base += __popcll(w[wi] & ((1ull << bi) - 1ull));   // bi in [0,60], no UB
#pragma unroll
    for (int i = 0; i < 4; ++i) {
        if ((w[wi] >> (bi + i)) & 1ull) { list[base] = (p + i) << 11; ++base; }
    }
    int tot = 0;
#pragma unroll
    for (int k = 0; k < 8; ++k) tot += pc[k];
    return tot;
}

// ---------------- scan kernel: 4 WGs (128 thr) per batch element -------------
// st layout: [z | v | i | b], each BB*NH floats.
// Exchange slots: slot(b,par,w) = flags + ((b*2+par)*8 + w)*16  (128 B each);
// slot[0]=mask (relaxed), slot[1]=tag=tglob+1 (release). w = q*2 + wave.
__global__ __launch_bounds__(128)
void lsnn_scan(const float* __restrict__ F, const float* __restrict__ wT,
               const float* __restrict__ z0, const float* __restrict__ v0,
               const float* __restrict__ i0, const float* __restrict__ b0,
               float* __restrict__ out, float* __restrict__ st,
               unsigned long long* __restrict__ flags,
               int t0, int Tc, int first, int last) {
    const int tid  = threadIdx.x;        // 0..127
    const int b    = blockIdx.x & 63;    // batch
    const int q    = blockIdx.x >> 6;    // quarter 0..3
    const int col  = (q << 7) + tid;     // owned column
    const int lane = tid & 63;
    const int wv   = tid >> 6;           // wave 0..1
    const size_t bn = (size_t)b * NH + col;

    __shared__ __align__(16) int list[NH + 2 * TS];
    __shared__ unsigned long long words[8];

    float v, cur, bb, zprev;
    if (first) {
        zprev = z0[bn]; v = v0[bn]; cur = i0[bn]; bb = b0[bn];
    } else {
        zprev = st[0 * BB * NH + bn];
        v     = st[1 * BB * NH + bn];
        cur   = st[2 * BB * NH + bn];
        bb    = st[3 * BB * NH + bn];
    }

    // ---- initial list: read the full z-plane of batch b directly -----------
    {
        const float* zsrc = first ? z0 : (st + 0 * BB * NH);
#pragma unroll
        for (int r = 0; r < 4; ++r) {
            const float zv = zsrc[(size_t)b * NH + (r << 7) + tid];
            const unsigned long long m = __ballot(zv > 0.0f);
            if (lane == 0) words[(r << 1) + wv] = m;
        }
        __syncthreads();
    }
    int cnt = build_list(words, list, tid);
    if (tid < 2 * TS) list[cnt + tid] = PADOFF;
    __syncthreads();

    const char*  wb = reinterpret_cast<const char*>(wT);   // uniform base (SGPR)
    const unsigned n4 = (unsigned)col * 4u;                // column byte offset
    const float* Fp = F + (size_t)b * NH + col;
    float* op = out + ((size_t)t0 * BB + b) * NH + col;

    for (int t = 0; t < Tc; ++t) {
        const int tglob = t0 + t;
        const int par   = tglob & 1;

        // ---- t.1: prefetch F, elementwise update, publish spikes ------------
        const float fval = Fp[(size_t)t * BB * NH];   // consumed after gather
        const float v_dec = __fadd_rn(v, __fmul_rn(KV, __fadd_rn(__fsub_rn(0.0f, v), cur)));
        const float i_dec = __fsub_rn(cur, __fmul_rn(KI, cur));
        const float b_dec = __fadd_rn(bb, __fmul_rn(KB, __fsub_rn(1.0f, bb)));
        const float zn = (__fsub_rn(v_dec, b_dec) > 0.0f) ? 1.0f : 0.0f;
        v  = (zn > 0.0f) ? 0.0f : v_dec;
        bb = __fadd_rn(b_dec, __fmul_rn(zn, KJ));
        op[0] = zn;
        op += (size_t)BB * NH;
        const unsigned long long mm = __ballot(zn > 0.0f);
        if (lane == 0) {
            unsigned long long* slot =
                flags + ((size_t)((b * 2 + par) * 8 + (q * 2 + wv)) * 16);
            __hip_atomic_store(&slot[0], mm, __ATOMIC_RELAXED,
                               __HIP_MEMORY_SCOPE_AGENT);
            __hip_atomic_store(&slot[1], (unsigned long long)(tglob + 1),
                               __ATOMIC_RELEASE, __HIP_MEMORY_SCOPE_AGENT);
        }

        // ---- t.2: pipelined serial gather over list (prev spikes) -----------
        float rec = 0.0f;
        if (cnt > 0) {
            const int* lp = list;
            float bufA[TS], bufB[TS];
            fill_tile(bufA, lp, 0, wb, n4);
            __builtin_amdgcn_sched_barrier(0);
            int kt = 0;
            for (;;) {
                fill_tile(bufB, lp, kt + TS, wb, n4);
                __builtin_amdgcn_sched_barrier(0);
                add_tile(bufA, rec);
                kt += TS;
                if (kt >= cnt) break;
                fill_tile(bufA, lp, kt + TS, wb, n4);
                __builtin_amdgcn_sched_barrier(0);
                add_tile(bufB, rec);
                kt += TS;
                if (kt >= cnt) break;
            }
        }
        cur = __fadd_rn(__fadd_rn(i_dec, fval), rec);
        zprev = zn;

        // ---- t.3: poll peers' slots, rebuild list for next step -------------
        if (t < Tc - 1) {
            if (tid < 8) {
                unsigned long long* slot =
                    flags + ((size_t)((b * 2 + par) * 8 + tid) * 16);
                const unsigned long long target =
                    (unsigned long long)(tglob + 1);
                int guard = 0;
                while (__hip_atomic_load(&slot[1], __ATOMIC_ACQUIRE,
                                         __HIP_MEMORY_SCOPE_AGENT) < target) {
                    __builtin_amdgcn_s_sleep(1);
                    if (++guard > (1 << 24)) break;   // wrong-answer > hang
                }
                words[tid] = __hip_atomic_load(&slot[0], __ATOMIC_ACQUIRE,
                                               __HIP_MEMORY_SCOPE_AGENT);
            }
            __syncthreads();   // words published; all gathers done
            cnt = build_list(words, list, tid);
            if (tid < 2 * TS) list[cnt + tid] = PADOFF;
            __syncthreads();   // list ready for next gather
        }
    }

    st[0 * BB * NH + bn] = zprev;
    st[1 * BB * NH + bn] = v;
    st[2 * BB * NH + bn] = cur;
    st[3 * BB * NH + bn] = bb;
    if (last) {
        float* tail = out + (size_t)TT * BB * NH;
        tail[0 * BB * NH + bn] = zprev;  // zT
        tail[1 * BB * NH + bn] = v;      // vT
        tail[2 * BB * NH + bn] = cur;    // iT
        tail[3 * BB * NH + bn] = bb;     // bT
    }
}

// ---------------------------------------------------------------------------
extern "C" void kernel_launch(void* const* d_in, const int* in_sizes, int n_in,
                              void* d_out, int out_size, void* d_ws, size_t ws_size,
                              hipStream_t stream) {
    const float* X     = (const float*)d_in[0];
    const float* z0    = (const float*)d_in[1];
    const float* v0    = (const float*)d_in[2];
    const float* i0    = (const float*)d_in[3];
    const float* b0    = (const float*)d_in[4];
    const float* w_in  = (const float*)d_in[5];
    const float* w_rec = (const float*)d_in[6];
    float* out = (float*)d_out;

    char* ws = (char*)d_ws;
    float* wT = (float*)ws;                                    // 1 MB + zero row
    const size_t wT_bytes = ((size_t)NH * NH + NH) * 4 + 2048;
    float* st = (float*)(ws + wT_bytes);                       // 512 KB
    unsigned long long* flags =
        (unsigned long long*)(ws + wT_bytes + (512u << 10));   // 128 KB slots
    char*  fbase = ws + wT_bytes + (512u << 10) + (128u << 10);

    const long long per = (long long)BB * NH * 4;              // bytes/step of F
    long long avail = (long long)ws_size -
                      (long long)(wT_bytes + (512u << 10) + (128u << 10));
    int Tc;
    if (avail >= 2 * per * TT) {
        Tc = TT;
    } else {
        Tc = (int)(avail / (2 * per));
        if (Tc > TT) Tc = TT;
        Tc &= ~1;
        if (Tc < 2) Tc = 2;
    }
    const size_t fbytes = (size_t)Tc * per;
    float* Fb[2] = { (float*)fbase, (float*)(fbase + fbytes) };

    transp512<<<dim3(16, 16), dim3(32, 8), 0, stream>>>(w_rec, wT);
    zrow<<<1, NH, 0, stream>>>(wT, flags);

    int t0 = 0, buf = 0;
    bool firstc = true;
    while (t0 < TT) {
        const int Tcur = (Tc < TT - t0) ? Tc : (TT - t0);
        const int Mc = Tcur * BB;
        gemm_ff<<<dim3(4, Mc / 128), 256, 0, stream>>>(
            X + (size_t)t0 * BB * NIN, w_in, Fb[buf], Mc);
        lsnn_scan<<<dim3(256), dim3(128), 0, stream>>>(
            Fb[buf], wT, z0, v0, i0, b0, out, st, flags,
            t0, Tcur, firstc ? 1 : 0, (t0 + Tcur >= TT) ? 1 : 0);
        firstc = false;
        buf ^= 1;
        t0 += Tcur;
    }
}

// Round 10
// 2735.602 us; speedup vs baseline: 5.1731x; 3.8273x over previous
//
#include <hip/hip_runtime.h>
#include <hip/hip_bf16.h>

// LSNN adaptive-LIF scan, T=1000, B=64, N_in=256, N_h=512, fp32.
//
// BITWISE CONSTRAINT (rounds 2-7): harness compares binary spikes exactly;
// flips cascade. The recurrent term for column n MUST be one serial
// ascending-index __fadd_rn chain over active neurons (== numpy/OpenBLAS
// sequential-k order; fma(0,w,c)=c). Pad rows are +0.0 (bitwise no-op).
//
// Round 10: r9's acquire/release fences emit buffer_inv -> per-XCD L2
// invalidated every step -> wT evicted -> gather at LLC speed (FETCH 69->102
// MB, 24.5k cy/step). Fix: FENCE-FREE exchange. Pack (tag<<32 | mask_half)
// into single u64 words stored/loaded with RELAXED agent-scope atomics
// (sc1, no cache maintenance -> L2 stays warm). Tag travels with data, so
// no ordering is needed; slot-overwrite safety follows from the r9 causal
// chain (writer reaches t+2 publish only after its t+1 poll saw the
// reader's t+1 publish, which is po-after the reader consumed t).

#define TT   1000
#define BB   64
#define NIN  256
#define NH   512
#define TS   16                          // gather tile size
#define PADOFF (NH * 2048)               // byte offset of zeroed row 512 of wT

__device__ constexpr float KV = (float)(0.001 * 100.0);            // DT*TAU_MEM_INV
__device__ constexpr float KI = (float)(0.001 * 200.0);            // DT*TAU_SYN_INV
__device__ constexpr float KB = (float)(0.001 * (1.0 / 800.0));    // DT*TAU_ADAPT_INV
__device__ constexpr float KJ = (float)((1.0 / 800.0) * 1.8);      // TAU_ADAPT_INV*BETA

// ---------------- transpose w_rec (512x512): wT[j][n] = w_rec[n][j] ----------
__global__ void transp512(const float* __restrict__ in, float* __restrict__ ot) {
    __shared__ float tile[32][33];
    const int tx = threadIdx.x;            // 0..31
    const int ty = threadIdx.y;            // 0..7
    const int jcol = blockIdx.x * 32 + tx;
    const int row0 = blockIdx.y * 32;
    for (int r = ty; r < 32; r += 8)
        tile[r][tx] = in[(size_t)(row0 + r) * NH + jcol];
    __syncthreads();
    const int ncol = blockIdx.y * 32 + tx;
    const int jrow0 = blockIdx.x * 32;
    for (int r = ty; r < 32; r += 8)
        ot[(size_t)(jrow0 + r) * NH + ncol] = tile[tx][r];
}

// zero row 512 of wT (padding target) + zero the exchange words (16 KB)
__global__ void zrow(float* __restrict__ wT, unsigned long long* __restrict__ flags) {
    wT[(size_t)NH * NH + threadIdx.x] = 0.0f;
    // words: 64 batches x 2 parities x 8 writers x 2 halves = 2048 u64
    for (int i = threadIdx.x; i < 2048; i += NH)
        flags[i] = 0ull;
}

// ---------------- fp32 GEMM: F[m][n] = sum_k X[m][k] * W[n][k] ---------------
// UNCHANGED from round 2 (bitwise-verified against the np reference).
__global__ __launch_bounds__(256)
void gemm_ff(const float* __restrict__ X, const float* __restrict__ W,
             float* __restrict__ F, int M) {
    const int bx = blockIdx.x;   // n-tile: 0..3
    const int by = blockIdx.y;   // m-tile
    const int tid = threadIdx.x;

    __shared__ float As[32][128];
    __shared__ float Bs[32][128];

    const int tn0 = (tid & 15) * 8;
    const int tm0 = (tid >> 4) * 8;
    float acc[8][8] = {};

    const int am = tid >> 1;
    const int aq = (tid & 1) * 4;

    const float* Xb = X + (size_t)(by * 128 + am) * NIN;
    const float* Wb = W + (size_t)(bx * 128 + am) * NIN;

    for (int k0 = 0; k0 < NIN; k0 += 32) {
        __syncthreads();
#pragma unroll
        for (int i2 = 0; i2 < 4; ++i2) {
            const int q = aq + i2;
            float4 xa = *reinterpret_cast<const float4*>(Xb + k0 + q * 4);
            As[q * 4 + 0][am] = xa.x; As[q * 4 + 1][am] = xa.y;
            As[q * 4 + 2][am] = xa.z; As[q * 4 + 3][am] = xa.w;
            float4 wa = *reinterpret_cast<const float4*>(Wb + k0 + q * 4);
            Bs[q * 4 + 0][am] = wa.x; Bs[q * 4 + 1][am] = wa.y;
            Bs[q * 4 + 2][am] = wa.z; Bs[q * 4 + 3][am] = wa.w;
        }
        __syncthreads();
#pragma unroll 8
        for (int kk = 0; kk < 32; ++kk) {
            float4 a0 = *reinterpret_cast<const float4*>(&As[kk][tm0]);
            float4 a1 = *reinterpret_cast<const float4*>(&As[kk][tm0 + 4]);
            float4 b0 = *reinterpret_cast<const float4*>(&Bs[kk][tn0]);
            float4 b1 = *reinterpret_cast<const float4*>(&Bs[kk][tn0 + 4]);
            const float av[8] = {a0.x, a0.y, a0.z, a0.w, a1.x, a1.y, a1.z, a1.w};
            const float bv[8] = {b0.x, b0.y, b0.z, b0.w, b1.x, b1.y, b1.z, b1.w};
#pragma unroll
            for (int i = 0; i < 8; ++i)
#pragma unroll
                for (int j = 0; j < 8; ++j)
                    acc[i][j] += av[i] * bv[j];
        }
    }

    float* Fo = F + (size_t)(by * 128 + tm0) * NH + bx * 128 + tn0;
#pragma unroll
    for (int i = 0; i < 8; ++i) {
        *reinterpret_cast<float4*>(Fo + (size_t)i * NH) =
            make_float4(acc[i][0], acc[i][1], acc[i][2], acc[i][3]);
        *reinterpret_cast<float4*>(Fo + (size_t)i * NH + 4) =
            make_float4(acc[i][4], acc[i][5], acc[i][6], acc[i][7]);
    }
}

// ---------------- gather tile helpers (r7-proven) ----------------------------
__device__ __forceinline__ void fill_tile(float (&buf)[TS], const int* lp,
                                          int base, const char* wb,
                                          unsigned n4) {
#pragma unroll
    for (int i = 0; i < TS; i += 4) {
        const int4 o = *reinterpret_cast<const int4*>(lp + base + i);
        buf[i + 0] = *reinterpret_cast<const float*>(wb + (unsigned)(o.x + (int)n4));
        buf[i + 1] = *reinterpret_cast<const float*>(wb + (unsigned)(o.y + (int)n4));
        buf[i + 2] = *reinterpret_cast<const float*>(wb + (unsigned)(o.z + (int)n4));
        buf[i + 3] = *reinterpret_cast<const float*>(wb + (unsigned)(o.w + (int)n4));
    }
}
__device__ __forceinline__ void add_tile(const float (&buf)[TS], float& rec) {
#pragma unroll
    for (int i = 0; i < TS; ++i) rec = __fadd_rn(rec, buf[i]);
}

// build ascending list from 16 x u32 halves in LDS; returns total count.
// thread tid handles bits 4*tid .. 4*tid+3 (128 threads x 4 = 512 bits).
__device__ __forceinline__ int build_list(const unsigned int* halves,
                                          int* list, int tid) {
    unsigned long long w[8];
    int pc[8];
#pragma unroll
    for (int k = 0; k < 8; ++k) {
        w[k] = (unsigned long long)halves[2 * k] |
               ((unsigned long long)halves[2 * k + 1] << 32);
        pc[k] = __popcll(w[k]);
    }
    const int p  = tid << 2;
    const int wi = p >> 6;
    const int bi = p & 63;
    int base = 0;
#pragma unroll
    for (int k = 0; k < 8; ++k) if (k < wi) base += pc[k];
    base += __popcll(w[wi] & ((1ull << bi) - 1ull));   // bi in [0,60], no UB
#pragma unroll
    for (int i = 0; i < 4; ++i) {
        if ((w[wi] >> (bi + i)) & 1ull) { list[base] = (p + i) << 11; ++base; }
    }
    int tot = 0;
#pragma unroll
    for (int k = 0; k < 8; ++k) tot += pc[k];
    return tot;
}

// ---------------- scan kernel: 4 WGs (128 thr) per batch element -------------
// st layout: [z | v | i | b], each BB*NH floats.
// Exchange words: flags[((b*2+par)*8 + w)*2 + h] = (tag32<<32)|mask_half,
// tag = tglob+1, writer w = q*2+wave, h = lo/hi half. 128B per (b,par).
__global__ __launch_bounds__(128)
void lsnn_scan(const float* __restrict__ F, const float* __restrict__ wT,
               const float* __restrict__ z0, const float* __restrict__ v0,
               const float* __restrict__ i0, const float* __restrict__ b0,
               float* __restrict__ out, float* __restrict__ st,
               unsigned long long* __restrict__ flags,
               int t0, int Tc, int first, int last) {
    const int tid  = threadIdx.x;        // 0..127
    const int b    = blockIdx.x & 63;    // batch
    const int q    = blockIdx.x >> 6;    // quarter 0..3
    const int col  = (q << 7) + tid;     // owned column
    const int lane = tid & 63;
    const int wv   = tid >> 6;           // wave 0..1
    const size_t bn = (size_t)b * NH + col;

    __shared__ __align__(16) int list[NH + 2 * TS];
    __shared__ unsigned int halves[16];

    float v, cur, bb, zprev;
    if (first) {
        zprev = z0[bn]; v = v0[bn]; cur = i0[bn]; bb = b0[bn];
    } else {
        zprev = st[0 * BB * NH + bn];
        v     = st[1 * BB * NH + bn];
        cur   = st[2 * BB * NH + bn];
        bb    = st[3 * BB * NH + bn];
    }

    // ---- initial list: read the full z-plane of batch b directly -----------
    {
        const float* zsrc = first ? z0 : (st + 0 * BB * NH);
#pragma unroll
        for (int r = 0; r < 4; ++r) {
            const float zv = zsrc[(size_t)b * NH + (r << 7) + tid];
            const unsigned long long m = __ballot(zv > 0.0f);
            if (lane == 0) {
                halves[((r << 1) + wv) * 2 + 0] = (unsigned int)m;
                halves[((r << 1) + wv) * 2 + 1] = (unsigned int)(m >> 32);
            }
        }
        __syncthreads();
    }
    int cnt = build_list(halves, list, tid);
    if (tid < 2 * TS) list[cnt + tid] = PADOFF;
    __syncthreads();

    const char*  wb = reinterpret_cast<const char*>(wT);   // uniform base (SGPR)
    const unsigned n4 = (unsigned)col * 4u;                // column byte offset
    const float* Fp = F + (size_t)b * NH + col;
    float* op = out + ((size_t)t0 * BB + b) * NH + col;

    for (int t = 0; t < Tc; ++t) {
        const int tglob = t0 + t;
        const int par   = tglob & 1;

        // ---- t.1: prefetch F, elementwise update, publish spikes ------------
        const float fval = Fp[(size_t)t * BB * NH];   // consumed after gather
        const float v_dec = __fadd_rn(v, __fmul_rn(KV, __fadd_rn(__fsub_rn(0.0f, v), cur)));
        const float i_dec = __fsub_rn(cur, __fmul_rn(KI, cur));
        const float b_dec = __fadd_rn(bb, __fmul_rn(KB, __fsub_rn(1.0f, bb)));
        const float zn = (__fsub_rn(v_dec, b_dec) > 0.0f) ? 1.0f : 0.0f;
        v  = (zn > 0.0f) ? 0.0f : v_dec;
        bb = __fadd_rn(b_dec, __fmul_rn(zn, KJ));
        op[0] = zn;
        op += (size_t)BB * NH;
        const unsigned long long mm = __ballot(zn > 0.0f);
        if (lane == 0) {
            // fire-and-forget packed publishes: RELAXED, no fences, L2 intact
            unsigned long long* sb = flags + (size_t)((b * 2 + par) * 16);
            const unsigned long long tag =
                ((unsigned long long)(unsigned int)(tglob + 1)) << 32;
            const int w = q * 2 + wv;
            __hip_atomic_store(&sb[w * 2 + 0],
                               tag | (mm & 0xffffffffull),
                               __ATOMIC_RELAXED, __HIP_MEMORY_SCOPE_AGENT);
            __hip_atomic_store(&sb[w * 2 + 1],
                               tag | (mm >> 32),
                               __ATOMIC_RELAXED, __HIP_MEMORY_SCOPE_AGENT);
        }

        // ---- t.2: pipelined serial gather over list (prev spikes) -----------
        float rec = 0.0f;
        if (cnt > 0) {
            const int* lp = list;
            float bufA[TS], bufB[TS];
            fill_tile(bufA, lp, 0, wb, n4);
            __builtin_amdgcn_sched_barrier(0);
            int kt = 0;
            for (;;) {
                fill_tile(bufB, lp, kt + TS, wb, n4);
                __builtin_amdgcn_sched_barrier(0);
                add_tile(bufA, rec);
                kt += TS;
                if (kt >= cnt) break;
                fill_tile(bufA, lp, kt + TS, wb, n4);
                __builtin_amdgcn_sched_barrier(0);
                add_tile(bufB, rec);
                kt += TS;
                if (kt >= cnt) break;
            }
        }
        cur = __fadd_rn(__fadd_rn(i_dec, fval), rec);
        zprev = zn;

        // ---- t.3: poll packed words (relaxed), rebuild list -----------------
        if (t < Tc - 1) {
            if (tid < 16) {
                unsigned long long* sb = flags + (size_t)((b * 2 + par) * 16);
                const unsigned int target = (unsigned int)(tglob + 1);
                unsigned long long vv;
                int guard = 0;
                for (;;) {
                    vv = __hip_atomic_load(&sb[tid], __ATOMIC_RELAXED,
                                           __HIP_MEMORY_SCOPE_AGENT);
                    if ((unsigned int)(vv >> 32) >= target) break;
                    __builtin_amdgcn_s_sleep(1);
                    if (++guard > (1 << 20)) break;   // wrong-answer > hang
                }
                halves[tid] = (unsigned int)vv;       // tag validated w/ data
            }
            __syncthreads();   // halves published; all gathers done
            cnt = build_list(halves, list, tid);
            if (tid < 2 * TS) list[cnt + tid] = PADOFF;
            __syncthreads();   // list ready for next gather
        }
    }

    st[0 * BB * NH + bn] = zprev;
    st[1 * BB * NH + bn] = v;
    st[2 * BB * NH + bn] = cur;
    st[3 * BB * NH + bn] = bb;
    if (last) {
        float* tail = out + (size_t)TT * BB * NH;
        tail[0 * BB * NH + bn] = zprev;  // zT
        tail[1 * BB * NH + bn] = v;      // vT
        tail[2 * BB * NH + bn] = cur;    // iT
        tail[3 * BB * NH + bn] = bb;     // bT
    }
}

// ---------------------------------------------------------------------------
extern "C" void kernel_launch(void* const* d_in, const int* in_sizes, int n_in,
                              void* d_out, int out_size, void* d_ws, size_t ws_size,
                              hipStream_t stream) {
    const float* X     = (const float*)d_in[0];
    const float* z0    = (const float*)d_in[1];
    const float* v0    = (const float*)d_in[2];
    const float* i0    = (const float*)d_in[3];
    const float* b0    = (const float*)d_in[4];
    const float* w_in  = (const float*)d_in[5];
    const float* w_rec = (const float*)d_in[6];
    float* out = (float*)d_out;

    char* ws = (char*)d_ws;
    float* wT = (float*)ws;                                    // 1 MB + zero row
    const size_t wT_bytes = ((size_t)NH * NH + NH) * 4 + 2048;
    float* st = (float*)(ws + wT_bytes);                       // 512 KB
    unsigned long long* flags =
        (unsigned long long*)(ws + wT_bytes + (512u << 10));   // 16 KB words
    char*  fbase = ws + wT_bytes + (512u << 10) + (16u << 10);

    const long long per = (long long)BB * NH * 4;              // bytes/step of F
    long long avail = (long long)ws_size -
                      (long long)(wT_bytes + (512u << 10) + (16u << 10));
    int Tc;
    if (avail >= 2 * per * TT) {
        Tc = TT;
    } else {
        Tc = (int)(avail / (2 * per));
        if (Tc > TT) Tc = TT;
        Tc &= ~1;
        if (Tc < 2) Tc = 2;
    }
    const size_t fbytes = (size_t)Tc * per;
    float* Fb[2] = { (float*)fbase, (float*)(fbase + fbytes) };

    transp512<<<dim3(16, 16), dim3(32, 8), 0, stream>>>(w_rec, wT);
    zrow<<<1, NH, 0, stream>>>(wT, flags);

    int t0 = 0, buf = 0;
    bool firstc = true;
    while (t0 < TT) {
        const int Tcur = (Tc < TT - t0) ? Tc : (TT - t0);
        const int Mc = Tcur * BB;
        gemm_ff<<<dim3(4, Mc / 128), 256, 0, stream>>>(
            X + (size_t)t0 * BB * NIN, w_in, Fb[buf], Mc);
        lsnn_scan<<<dim3(256), dim3(128), 0, stream>>>(
            Fb[buf], wT, z0, v0, i0, b0, out, st, flags,
            t0, Tcur, firstc ? 1 : 0, (t0 + Tcur >= TT) ? 1 : 0);
        firstc = false;
        buf ^= 1;
        t0 += Tcur;
    }
}